// Round 1
// baseline (248.500 us; speedup 1.0000x reference)
//
#include <hip/hip_runtime.h>

// PointPillarsScatter: out(B=4, C=64, NY=496, NX=432) <- scatter of
// voxel_features(N=64000, 64) at coors(N,4)=[b,z,y,x]. Duplicates: last wins.
//
// Strategy: inverse-index gather.
//   pass 0: memset winner map ws[B*NY*NX] = -1   (hipMemsetAsync 0xFF)
//   pass 1: atomicMax(&ws[b*NPIX + y*NX + x], n) -> winner = max n = last occurrence
//   pass 2: for every output element (coalesced float4): n = ws[...]; out = n>=0 ? vf[n*64+c] : 0
// This writes the 219 MB output exactly once (no zero-fill + overwrite) and keeps
// the scattered accesses (vf gathers, 16.4 MB) L3-resident.

#define C_CH 64
#define NY_ 496
#define NX_ 432
#define NPIX (NY_ * NX_)      // 214272
#define NVOX 64000
#define BATCH_ 4
#define PIX4 (NPIX / 4)       // 53568 float4 groups per (b,c) plane

__global__ void pps_winners(const int* __restrict__ coors, int* __restrict__ ws, int n) {
    int i = blockIdx.x * blockDim.x + threadIdx.x;
    if (i >= n) return;
    const int4 cv = reinterpret_cast<const int4*>(coors)[i];  // [b, z, y, x]
    int flat = cv.x * NPIX + cv.z * NX_ + cv.w;
    atomicMax(&ws[flat], i);  // ws pre-set to -1; max index == last occurrence (np semantics)
}

__global__ void pps_gather(const float* __restrict__ vf,
                           const int* __restrict__ ws,
                           float* __restrict__ out) {
    // One thread per 4 consecutive x of one (b,c) plane. tid = bc * PIX4 + p4.
    long tid = (long)blockIdx.x * blockDim.x + threadIdx.x;
    int bc = (int)(tid / PIX4);          // compile-time const divisor -> magic mul
    int p4 = (int)(tid - (long)bc * PIX4);
    int b = bc >> 6;
    int c = bc & 63;
    int pix = p4 * 4;

    const int4 w = *reinterpret_cast<const int4*>(&ws[b * NPIX + pix]);  // coalesced 16B
    float4 o;
    o.x = (w.x >= 0) ? vf[(long)w.x * C_CH + c] : 0.0f;
    o.y = (w.y >= 0) ? vf[(long)w.y * C_CH + c] : 0.0f;
    o.z = (w.z >= 0) ? vf[(long)w.z * C_CH + c] : 0.0f;
    o.w = (w.w >= 0) ? vf[(long)w.w * C_CH + c] : 0.0f;
    *reinterpret_cast<float4*>(&out[(long)bc * NPIX + pix]) = o;         // coalesced 16B store
}

extern "C" void kernel_launch(void* const* d_in, const int* in_sizes, int n_in,
                              void* d_out, int out_size, void* d_ws, size_t ws_size,
                              hipStream_t stream) {
    const float* vf = (const float*)d_in[0];   // (64000, 64) f32
    const int* coors = (const int*)d_in[1];    // (64000, 4)  i32
    float* out = (float*)d_out;                // (4, 64, 496, 432) f32
    int* ws = (int*)d_ws;                      // winner map: BATCH_*NPIX ints = 3.4 MB

    // ws = -1 everywhere (0xFF bytes == -1 as int32)
    hipMemsetAsync(ws, 0xFF, (size_t)BATCH_ * NPIX * sizeof(int), stream);

    // pass 1: winner resolution (last duplicate wins via atomicMax on index)
    {
        int threads = 256;
        int blocks = (NVOX + threads - 1) / threads;
        pps_winners<<<blocks, threads, 0, stream>>>(coors, ws, NVOX);
    }

    // pass 2: coalesced gather into output
    {
        long total = (long)BATCH_ * C_CH * PIX4;  // 13,713,408 threads
        int threads = 256;
        long blocks = (total + threads - 1) / threads;  // 53568
        pps_gather<<<(int)blocks, threads, 0, stream>>>(vf, ws, out);
    }
}